// Round 8
// baseline (37.403 us; speedup 1.0000x reference)
//
#include <hip/hip_runtime.h>
#include <cmath>

constexpr int Bn = 2, Hn = 256, Wn = 256, Cn = 2;
// Block = (b, w-pair): 4 "wq" columns = (w0 + (q>>1), c = q&1).
// 1024 threads: compute thread = (ig = t>>6 in [0,16), jl = t&63).
// Each thread: 16 i's (4 quads) x 4 wq x 4 j's (jl + 64*jj) = 256 terms.

__global__ __launch_bounds__(1024, 4) void sinc_main_kernel(
    const float* __restrict__ img, const float* __restrict__ fmap,
    float* __restrict__ out)
{
    const float INV_PI = 0x1.45f306p-2f;  // float32(1/pi)

    __shared__ __align__(16) float sh_x[4][Hn];   // [wq][i] : quad reads along i
    __shared__ __align__(16) float sh_p[4][Hn];   // img * sin(pi*x0)/pi
    __shared__ __align__(16) float sh_acc[8][Hn * 4];  // 32 KB folded partials

    const int b  = blockIdx.x >> 7;          // grid = 2 * 128
    const int w0 = (blockIdx.x & 127) * 2;   // first w of the pair
    const int t  = threadIdx.x;

    // ---- Stage: thread t owns (i = t>>2, q = t&3); 16B-contiguous chunks. ----
    {
        const int i = t >> 2, q = t & 3;
        // ((b*Hn + i)*Wn + (w0 + (q>>1)))*Cn + (q&1) == base + i*512 + w0*2 + q
        const size_t off = ((size_t)b * Hn + i) * (Wn * Cn) + w0 * 2 + q;
        const float f = fmap[off];
        float x0 = fminf(fmaxf(f + (float)i, 0.0f), 255.0f);
        const float n = rintf(x0);
        const float r = x0 - n;                              // [-0.5, 0.5]
        float sp = __builtin_amdgcn_sinf(0.5f * r) * INV_PI; // sin(pi*x0)/pi mag
        if (((int)n) & 1) sp = -sp;
        const float p = img[off] * sp;
        // Nudge: p==0 ⟺ row contributes nothing; shift x0 so d is never 0.
        if (p == 0.0f) x0 += 0x1p-15f;
        sh_x[q][i] = x0;
        sh_p[q][i] = p;
    }
    __syncthreads();

    // ---- Compute: stable factored quad-merge, one rcp per 4 terms. ----
    const int ig = t >> 6;
    const int jl = t & 63;

    float acc[4][4];   // [jj][wq]
#pragma unroll
    for (int jj = 0; jj < 4; ++jj)
#pragma unroll
        for (int wq = 0; wq < 4; ++wq) acc[jj][wq] = 0.0f;

    const float4* qx = (const float4*)sh_x;   // index: wq*64 + quad
    const float4* qp = (const float4*)sh_p;

#pragma unroll
    for (int qd = 0; qd < 4; ++qd) {          // 4 quads of 4 consecutive i's
        const int iq = ig * 4 + qd;
        float4 xv[4], pv[4];
#pragma unroll
        for (int wq = 0; wq < 4; ++wq) {
            xv[wq] = qx[wq * 64 + iq];
            pv[wq] = qp[wq * 64 + iq];
        }
#pragma unroll
        for (int jj = 0; jj < 4; ++jj) {
            const float J = (float)(jl + 64 * jj);
#pragma unroll
            for (int wq = 0; wq < 4; ++wq) {
                const float d0 = xv[wq].x - J, d1 = xv[wq].y - J;
                const float d2 = xv[wq].z - J, d3 = xv[wq].w - J;
                const float m01 = d0 * d1, m23 = d2 * d3;
                const float n01 = fmaf(pv[wq].x, d1, pv[wq].y * d0);
                const float n23 = fmaf(pv[wq].z, d3, pv[wq].w * d2);
                const float Nv  = fmaf(n01, m23, n23 * m01);
                const float Dv  = m01 * m23;
                acc[jj][wq] = fmaf(Nv, __builtin_amdgcn_rcpf(Dv), acc[jj][wq]);
            }
        }
    }

    // ---- Fold 16 -> 8 groups (race-free two-phase), then reduce 8. ----
    if (ig >= 8) {
#pragma unroll
        for (int jj = 0; jj < 4; ++jj)
            *(float4*)&sh_acc[ig - 8][(jl + 64 * jj) * 4] = *(const float4*)acc[jj];
    }
    __syncthreads();
    if (ig < 8) {
#pragma unroll
        for (int jj = 0; jj < 4; ++jj) {
            float4* s = (float4*)&sh_acc[ig][(jl + 64 * jj) * 4];
            float4 v = *s;
            v.x += acc[jj][0]; v.y += acc[jj][1];
            v.z += acc[jj][2]; v.w += acc[jj][3];
            *s = v;
        }
    }
    __syncthreads();

    // ---- Final: thread t owns slot (j = t>>2, wq = t&3). ----
    {
        float a = 0.0f;
#pragma unroll
        for (int g = 0; g < 8; ++g) a += sh_acc[g][t];
        const int j = t >> 2;
        const float sgn = (j & 1) ? -1.0f : 1.0f;   // (-1)^j folded back in
        out[((size_t)b * Hn + j) * (Wn * Cn) + w0 * 2 + (t & 3)] = sgn * a;
    }
}

extern "C" void kernel_launch(void* const* d_in, const int* in_sizes, int n_in,
                              void* d_out, int out_size, void* d_ws, size_t ws_size,
                              hipStream_t stream)
{
    (void)in_sizes; (void)n_in; (void)out_size; (void)d_ws; (void)ws_size;
    const float* img  = (const float*)d_in[0];
    const float* fmap = (const float*)d_in[1];
    float* out = (float*)d_out;
    sinc_main_kernel<<<Bn * (Wn / 2), 1024, 0, stream>>>(img, fmap, out);
}